// Round 1
// baseline (280.587 us; speedup 1.0000x reference)
//
#include <hip/hip_runtime.h>
#include <math.h>

#define B_ 2
#define N_ 20000
#define C_ 64
#define K_ 16
#define CS_ 16
#define EPS_ 1e-5f

// ---------------------------------------------------------------------------
// Kernel A: 1x1 conv projections. xq = wq@q+bq, xk = wk@k+bk, xv = wv@q+bv.
// Output layout [B*N][C] (point-major) so kernel B's gather reads are
// 256B-contiguous per neighbor.
// Each thread owns half a point (32 output channels), holds full 64-float
// q/k columns in VGPRs; weight rows are wave-uniform -> s_load.
// ---------------------------------------------------------------------------
__device__ __forceinline__ void matvec_rows(const float* __restrict__ W,
                                            const float* __restrict__ bias,
                                            const float (&x)[C_],
                                            float* __restrict__ outp, int co0)
{
    for (int co = co0; co < co0 + 32; co += 4) {
        float a0 = bias[co + 0], a1 = bias[co + 1], a2 = bias[co + 2], a3 = bias[co + 3];
#pragma unroll
        for (int ci = 0; ci < C_; ci++) {
            float xv = x[ci];
            a0 = fmaf(W[(co + 0) * C_ + ci], xv, a0);
            a1 = fmaf(W[(co + 1) * C_ + ci], xv, a1);
            a2 = fmaf(W[(co + 2) * C_ + ci], xv, a2);
            a3 = fmaf(W[(co + 3) * C_ + ci], xv, a3);
        }
        float4 st = make_float4(a0, a1, a2, a3);
        *reinterpret_cast<float4*>(outp + co) = st;
    }
}

__global__ __launch_bounds__(64) void proj_kernel(
    const float* __restrict__ q, const float* __restrict__ kin,
    const float* __restrict__ wq, const float* __restrict__ bq,
    const float* __restrict__ wk, const float* __restrict__ bk,
    const float* __restrict__ wv, const float* __restrict__ bv,
    float* __restrict__ xq_t, float* __restrict__ xk_t, float* __restrict__ xv_t)
{
    int gid = blockIdx.x * 64 + threadIdx.x;
    if (gid >= B_ * N_ * 2) return;
    int pt   = gid >> 1;          // point index 0..B*N-1
    int half = gid & 1;           // which 32 output channels
    int b = pt / N_;
    int n = pt - b * N_;

    const float* qcol = q   + (size_t)b * C_ * N_ + n;
    const float* kcol = kin + (size_t)b * C_ * N_ + n;
    float qr[C_], kr[C_];
#pragma unroll
    for (int ci = 0; ci < C_; ci++) {
        qr[ci] = qcol[(size_t)ci * N_];   // coalesced-ish across lanes
        kr[ci] = kcol[(size_t)ci * N_];
    }
    int co0 = half * 32;
    matvec_rows(wq, bq, qr, xq_t + (size_t)pt * C_, co0);
    matvec_rows(wv, bv, qr, xv_t + (size_t)pt * C_, co0);
    matvec_rows(wk, bk, kr, xk_t + (size_t)pt * C_, co0);
}

// ---------------------------------------------------------------------------
// Kernel B: per-point attention. One wave (64 threads) per point.
// Phase 1 (lane = channel c): gather neighbor xk/xv/coord, positional MLP,
//   w = relu(bn1(xk - xq + pr)); stage w and v=xv+pr in LDS.
// Phase 2 (lane -> g = lane&15, k-quad = lane>>4): u = w1_w @ w (64 MACs x4),
//   bn2/relu, t = w2_w @ z, softmax over 16 k via __shfl_xor(16),(32).
// Phase 3 (lane = channel c): out[c] = sum_k v[k][c] * soft[k][c%16].
// ---------------------------------------------------------------------------
__global__ __launch_bounds__(64) void attn_kernel(
    const float* __restrict__ coord, const int* __restrict__ nbr,
    const float* __restrict__ xq_t, const float* __restrict__ xk_t,
    const float* __restrict__ xv_t,
    const float* __restrict__ p1_w, const float* __restrict__ p1_b,
    const float* __restrict__ p_bn_g, const float* __restrict__ p_bn_b,
    const float* __restrict__ p_bn_m, const float* __restrict__ p_bn_v,
    const float* __restrict__ p2_w, const float* __restrict__ p2_b,
    const float* __restrict__ w_bn1_g, const float* __restrict__ w_bn1_b,
    const float* __restrict__ w_bn1_m, const float* __restrict__ w_bn1_v,
    const float* __restrict__ w1_w, const float* __restrict__ w1_b,
    const float* __restrict__ w_bn2_g, const float* __restrict__ w_bn2_b,
    const float* __restrict__ w_bn2_m, const float* __restrict__ w_bn2_v,
    const float* __restrict__ w2_w, const float* __restrict__ w2_b,
    float* __restrict__ out_t)
{
    constexpr int WS = 76;  // LDS row stride (floats): 304B = 16B-aligned, k-groups land 2 banks apart
    constexpr int ZS = 18;  // stride for [K][CS] buffers
    __shared__ float wbuf[K_ * WS];
    __shared__ float vbuf[K_ * WS];
    __shared__ float zbuf[K_ * ZS];
    __shared__ float sbuf[K_ * ZS];

    int bn = blockIdx.x;          // = b*N + n
    int b  = bn / N_;
    int c  = threadIdx.x;

    // per-lane constants, BN affine folded
    float xq   = xq_t[bn * C_ + c];
    float p2w0 = p2_w[c * 3 + 0], p2w1 = p2_w[c * 3 + 1], p2w2 = p2_w[c * 3 + 2];
    float p2b  = p2_b[c];
    float bn1s = w_bn1_g[c] * rsqrtf(w_bn1_v[c] + EPS_);
    float bn1b = w_bn1_b[c] - w_bn1_m[c] * bn1s;

    float p1w[9], pbs[3], pbb[3];
#pragma unroll
    for (int j = 0; j < 9; j++) p1w[j] = p1_w[j];
#pragma unroll
    for (int j = 0; j < 3; j++) {
        float s = p_bn_g[j] * rsqrtf(p_bn_v[j] + EPS_);
        pbs[j] = s;
        pbb[j] = (p1_b[j] - p_bn_m[j]) * s + p_bn_b[j];
    }

    const int* nb = nbr + bn * K_;
    for (int kk = 0; kk < K_; kk++) {
        int idx = nb[kk];
        int src = b * N_ + idx;
        float cx = coord[src * 3 + 0];
        float cy = coord[src * 3 + 1];
        float cz = coord[src * 3 + 2];
        float h0 = fmaxf(0.f, (p1w[0]*cx + p1w[1]*cy + p1w[2]*cz) * pbs[0] + pbb[0]);
        float h1 = fmaxf(0.f, (p1w[3]*cx + p1w[4]*cy + p1w[5]*cz) * pbs[1] + pbb[1]);
        float h2 = fmaxf(0.f, (p1w[6]*cx + p1w[7]*cy + p1w[8]*cz) * pbs[2] + pbb[2]);
        float pr = fmaf(p2w0, h0, fmaf(p2w1, h1, fmaf(p2w2, h2, p2b)));
        float xk = xk_t[src * C_ + c];   // 256B-contiguous gather
        float xv = xv_t[src * C_ + c];
        float wv_ = fmaxf(0.f, (xk - xq + pr) * bn1s + bn1b);
        wbuf[kk * WS + c] = wv_;
        vbuf[kk * WS + c] = xv + pr;
    }
    __syncthreads();

    // phase 2a: u[g, k] = w1_w[g,:] . wbuf[k,:]
    int g  = c & 15;
    int kb = (c >> 4) * 4;
    float u0 = 0.f, u1 = 0.f, u2 = 0.f, u3 = 0.f;
    const float4* w1r = reinterpret_cast<const float4*>(w1_w + g * C_);
#pragma unroll
    for (int c4 = 0; c4 < 16; c4++) {
        float4 wr = w1r[c4];
        float4 b0 = *reinterpret_cast<const float4*>(&wbuf[(kb + 0) * WS + c4 * 4]);
        float4 b1 = *reinterpret_cast<const float4*>(&wbuf[(kb + 1) * WS + c4 * 4]);
        float4 b2 = *reinterpret_cast<const float4*>(&wbuf[(kb + 2) * WS + c4 * 4]);
        float4 b3 = *reinterpret_cast<const float4*>(&wbuf[(kb + 3) * WS + c4 * 4]);
        u0 = fmaf(wr.x, b0.x, u0); u0 = fmaf(wr.y, b0.y, u0); u0 = fmaf(wr.z, b0.z, u0); u0 = fmaf(wr.w, b0.w, u0);
        u1 = fmaf(wr.x, b1.x, u1); u1 = fmaf(wr.y, b1.y, u1); u1 = fmaf(wr.z, b1.z, u1); u1 = fmaf(wr.w, b1.w, u1);
        u2 = fmaf(wr.x, b2.x, u2); u2 = fmaf(wr.y, b2.y, u2); u2 = fmaf(wr.z, b2.z, u2); u2 = fmaf(wr.w, b2.w, u2);
        u3 = fmaf(wr.x, b3.x, u3); u3 = fmaf(wr.y, b3.y, u3); u3 = fmaf(wr.z, b3.z, u3); u3 = fmaf(wr.w, b3.w, u3);
    }
    float w1bb = w1_b[g];
    float bn2s = w_bn2_g[g] * rsqrtf(w_bn2_v[g] + EPS_);
    float bn2b = w_bn2_b[g] - w_bn2_m[g] * bn2s;
    zbuf[(kb + 0) * ZS + g] = fmaxf(0.f, (u0 + w1bb) * bn2s + bn2b);
    zbuf[(kb + 1) * ZS + g] = fmaxf(0.f, (u1 + w1bb) * bn2s + bn2b);
    zbuf[(kb + 2) * ZS + g] = fmaxf(0.f, (u2 + w1bb) * bn2s + bn2b);
    zbuf[(kb + 3) * ZS + g] = fmaxf(0.f, (u3 + w1bb) * bn2s + bn2b);
    __syncthreads();

    // phase 2b: t[g2=g, k] = w2_b[g] + sum_gg w2_w[g,gg] * z[gg, k]
    float t0 = w2_b[g], t1 = t0, t2 = t0, t3 = t0;
#pragma unroll
    for (int gg = 0; gg < 16; gg++) {
        float w2 = w2_w[g * 16 + gg];
        t0 = fmaf(w2, zbuf[(kb + 0) * ZS + gg], t0);
        t1 = fmaf(w2, zbuf[(kb + 1) * ZS + gg], t1);
        t2 = fmaf(w2, zbuf[(kb + 2) * ZS + gg], t2);
        t3 = fmaf(w2, zbuf[(kb + 3) * ZS + gg], t3);
    }

    // softmax over the 16 k's for this g: 4 local + lanes {g, g+16, g+32, g+48}
    float m = fmaxf(fmaxf(t0, t1), fmaxf(t2, t3));
    m = fmaxf(m, __shfl_xor(m, 16));
    m = fmaxf(m, __shfl_xor(m, 32));
    float e0 = expf(t0 - m), e1 = expf(t1 - m), e2 = expf(t2 - m), e3 = expf(t3 - m);
    float s = e0 + e1 + e2 + e3;
    s += __shfl_xor(s, 16);
    s += __shfl_xor(s, 32);
    float inv = 1.0f / s;
    sbuf[(kb + 0) * ZS + g] = e0 * inv;
    sbuf[(kb + 1) * ZS + g] = e1 * inv;
    sbuf[(kb + 2) * ZS + g] = e2 * inv;
    sbuf[(kb + 3) * ZS + g] = e3 * inv;
    __syncthreads();

    // phase 3: out[c] = sum_k v[k][c] * soft[k][c & 15]
    float acc = 0.f;
#pragma unroll
    for (int kk = 0; kk < K_; kk++)
        acc = fmaf(vbuf[kk * WS + c], sbuf[kk * ZS + g], acc);
    out_t[bn * C_ + c] = acc;   // coalesced [point][channel]
}

// ---------------------------------------------------------------------------
// Kernel C: transpose [B, N, C] -> [B, C, N], 64x64 LDS tiles.
// ---------------------------------------------------------------------------
__global__ __launch_bounds__(256) void transpose_kernel(const float* __restrict__ src,
                                                        float* __restrict__ dst)
{
    __shared__ float tile[64][65];
    int b  = blockIdx.y;
    int n0 = blockIdx.x * 64;
    int t  = threadIdx.x;

    int p  = t >> 2;
    int c0 = (t & 3) * 16;
    int n  = n0 + p;
    if (n < N_) {
        const float4* s = reinterpret_cast<const float4*>(src + ((size_t)b * N_ + n) * C_ + c0);
#pragma unroll
        for (int j = 0; j < 4; j++) {
            float4 v = s[j];
            tile[p][c0 + j * 4 + 0] = v.x;
            tile[p][c0 + j * 4 + 1] = v.y;
            tile[p][c0 + j * 4 + 2] = v.z;
            tile[p][c0 + j * 4 + 3] = v.w;
        }
    }
    __syncthreads();

    int n_off = t & 63;
    int cg    = t >> 6;   // 0..3
    if (n0 + n_off < N_) {
#pragma unroll
        for (int j = 0; j < 16; j++) {
            int cc = cg * 16 + j;
            dst[(size_t)b * C_ * N_ + (size_t)cc * N_ + n0 + n_off] = tile[n_off][cc];
        }
    }
}

// ---------------------------------------------------------------------------
extern "C" void kernel_launch(void* const* d_in, const int* in_sizes, int n_in,
                              void* d_out, int out_size, void* d_ws, size_t ws_size,
                              hipStream_t stream)
{
    const float* coord = (const float*)d_in[0];
    const float* q     = (const float*)d_in[1];
    const float* k     = (const float*)d_in[2];
    const int*   nbr   = (const int*)d_in[3];
    const float* wq = (const float*)d_in[4];
    const float* bq = (const float*)d_in[5];
    const float* wk = (const float*)d_in[6];
    const float* bk = (const float*)d_in[7];
    const float* wv = (const float*)d_in[8];
    const float* bv = (const float*)d_in[9];
    const float* p1_w = (const float*)d_in[10];
    const float* p1_b = (const float*)d_in[11];
    const float* p_bn_g = (const float*)d_in[12];
    const float* p_bn_b = (const float*)d_in[13];
    const float* p_bn_m = (const float*)d_in[14];
    const float* p_bn_v = (const float*)d_in[15];
    const float* p2_w = (const float*)d_in[16];
    const float* p2_b = (const float*)d_in[17];
    const float* w_bn1_g = (const float*)d_in[18];
    const float* w_bn1_b = (const float*)d_in[19];
    const float* w_bn1_m = (const float*)d_in[20];
    const float* w_bn1_v = (const float*)d_in[21];
    const float* w1_w = (const float*)d_in[22];
    const float* w1_b = (const float*)d_in[23];
    const float* w_bn2_g = (const float*)d_in[24];
    const float* w_bn2_b = (const float*)d_in[25];
    const float* w_bn2_m = (const float*)d_in[26];
    const float* w_bn2_v = (const float*)d_in[27];
    const float* w2_w = (const float*)d_in[28];
    const float* w2_b = (const float*)d_in[29];

    const size_t PTS = (size_t)B_ * N_;        // 40000
    float* ws   = (float*)d_ws;
    float* xq_t = ws;                          // [PTS][64]
    float* xk_t = ws + PTS * C_;               // [PTS][64]
    float* xv_t = ws + 2 * PTS * C_;           // [PTS][64]
    float* out_t = xq_t;  // safe alias: block bn reads xq_t[bn] before writing out_t[bn]

    proj_kernel<<<(B_ * N_ * 2 + 63) / 64, 64, 0, stream>>>(
        q, k, wq, bq, wk, bk, wv, bv, xq_t, xk_t, xv_t);

    attn_kernel<<<B_ * N_, 64, 0, stream>>>(
        coord, nbr, xq_t, xk_t, xv_t,
        p1_w, p1_b, p_bn_g, p_bn_b, p_bn_m, p_bn_v, p2_w, p2_b,
        w_bn1_g, w_bn1_b, w_bn1_m, w_bn1_v, w1_w, w1_b,
        w_bn2_g, w_bn2_b, w_bn2_m, w_bn2_v, w2_w, w2_b,
        out_t);

    transpose_kernel<<<dim3((N_ + 63) / 64, B_), 256, 0, stream>>>(
        out_t, (float*)d_out);
}

// Round 2
// 154.404 us; speedup vs baseline: 1.8172x; 1.8172x over previous
//
#include <hip/hip_runtime.h>
#include <math.h>

#define B_ 2
#define N_ 20000
#define C_ 64
#define K_ 16
#define CS_ 16
#define EPS_ 1e-5f

// ---------------------------------------------------------------------------
// Kernel A: 1x1 conv projections, tiled mini-GEMM.
// Block = 256 threads = 4 waves, handles 64 points.
// - input tile staged in LDS [ci][p] (coalesced loads, conflict-free)
// - each wave owns a wave-uniform group of 16 output channels ->
//   weight reads are scalar s_loads (readfirstlane-forced)
// - outputs staged through LDS so global stores are contiguous float4s
// Output layout [B*N][C] (point-major) so kernel B's gathers read 256B rows.
// ---------------------------------------------------------------------------
__device__ __forceinline__ void mv16(const float* __restrict__ W,
                                     const float* __restrict__ bias,
                                     int ob, const float (&x)[C_], float (&acc)[16])
{
#pragma unroll
    for (int jg = 0; jg < 4; jg++) {
        const float* r0 = W + (size_t)(ob + jg * 4) * C_;
        const float* r1 = r0 + C_;
        const float* r2 = r0 + 2 * C_;
        const float* r3 = r0 + 3 * C_;
        float a0 = bias[ob + jg * 4 + 0];
        float a1 = bias[ob + jg * 4 + 1];
        float a2 = bias[ob + jg * 4 + 2];
        float a3 = bias[ob + jg * 4 + 3];
#pragma unroll
        for (int ci = 0; ci < C_; ci++) {
            float xc = x[ci];
            a0 = fmaf(r0[ci], xc, a0);
            a1 = fmaf(r1[ci], xc, a1);
            a2 = fmaf(r2[ci], xc, a2);
            a3 = fmaf(r3[ci], xc, a3);
        }
        acc[jg * 4 + 0] = a0; acc[jg * 4 + 1] = a1;
        acc[jg * 4 + 2] = a2; acc[jg * 4 + 3] = a3;
    }
}

__global__ __launch_bounds__(256) void proj_kernel(
    const float* __restrict__ q, const float* __restrict__ kin,
    const float* __restrict__ wq, const float* __restrict__ bq,
    const float* __restrict__ wk, const float* __restrict__ bk,
    const float* __restrict__ wv, const float* __restrict__ bv,
    float* __restrict__ xq_t, float* __restrict__ xk_t, float* __restrict__ xv_t)
{
    __shared__ float tin[C_][65];
    __shared__ float tout[C_][65];

    const int t      = threadIdx.x;
    const int lane_p = t & 63;
    const int pt0    = blockIdx.x * 64;
    const int pt     = pt0 + lane_p;
    const int b      = pt / N_;
    const int n      = pt - b * N_;
    const size_t cbase = (size_t)b * C_ * N_ + n;

    const int oq = __builtin_amdgcn_readfirstlane(t >> 6);  // wave-uniform channel group
    const int ob = oq * 16;

    // store helper indices (coalesced float4 stores)
    const int s_p  = t >> 2;          // 0..63 point within tile
    const int s_c0 = (t & 3) * 16;    // 16-channel chunk

    // ---- Q tile: xq = wq@q+bq, xv = wv@q+bv ----
#pragma unroll
    for (int r = 0; r < 16; r++) {
        int ci = ob + r;
        tin[ci][lane_p] = q[cbase + (size_t)ci * N_];   // coalesced (ci wave-uniform)
    }
    __syncthreads();

    float x[C_];
#pragma unroll
    for (int ci = 0; ci < C_; ci++) x[ci] = tin[ci][lane_p];  // conflict-free columns

    float accq[16], accv[16];
    mv16(wq, bq, ob, x, accq);
    mv16(wv, bv, ob, x, accv);

    // stage + store xq
#pragma unroll
    for (int j = 0; j < 16; j++) tout[ob + j][lane_p] = accq[j];
    __syncthreads();
    {
        float4* dp = reinterpret_cast<float4*>(xq_t + (size_t)(pt0 + s_p) * C_ + s_c0);
#pragma unroll
        for (int j4 = 0; j4 < 4; j4++) {
            float4 v;
            v.x = tout[s_c0 + j4 * 4 + 0][s_p];
            v.y = tout[s_c0 + j4 * 4 + 1][s_p];
            v.z = tout[s_c0 + j4 * 4 + 2][s_p];
            v.w = tout[s_c0 + j4 * 4 + 3][s_p];
            dp[j4] = v;
        }
    }
    __syncthreads();

    // stage + store xv
#pragma unroll
    for (int j = 0; j < 16; j++) tout[ob + j][lane_p] = accv[j];
    __syncthreads();
    {
        float4* dp = reinterpret_cast<float4*>(xv_t + (size_t)(pt0 + s_p) * C_ + s_c0);
#pragma unroll
        for (int j4 = 0; j4 < 4; j4++) {
            float4 v;
            v.x = tout[s_c0 + j4 * 4 + 0][s_p];
            v.y = tout[s_c0 + j4 * 4 + 1][s_p];
            v.z = tout[s_c0 + j4 * 4 + 2][s_p];
            v.w = tout[s_c0 + j4 * 4 + 3][s_p];
            dp[j4] = v;
        }
    }
    __syncthreads();

    // ---- K tile: xk = wk@k+bk ----
#pragma unroll
    for (int r = 0; r < 16; r++) {
        int ci = ob + r;
        tin[ci][lane_p] = kin[cbase + (size_t)ci * N_];
    }
    __syncthreads();
#pragma unroll
    for (int ci = 0; ci < C_; ci++) x[ci] = tin[ci][lane_p];

    float acck[16];
    mv16(wk, bk, ob, x, acck);
#pragma unroll
    for (int j = 0; j < 16; j++) tout[ob + j][lane_p] = acck[j];
    __syncthreads();
    {
        float4* dp = reinterpret_cast<float4*>(xk_t + (size_t)(pt0 + s_p) * C_ + s_c0);
#pragma unroll
        for (int j4 = 0; j4 < 4; j4++) {
            float4 v;
            v.x = tout[s_c0 + j4 * 4 + 0][s_p];
            v.y = tout[s_c0 + j4 * 4 + 1][s_p];
            v.z = tout[s_c0 + j4 * 4 + 2][s_p];
            v.w = tout[s_c0 + j4 * 4 + 3][s_p];
            dp[j4] = v;
        }
    }
}

// ---------------------------------------------------------------------------
// Kernel B: per-point attention. One wave (64 threads) per point.
// Phase 1 (lane = channel c): batched gather (all indices prefetched, all
//   loads issued before consumption), positional MLP, stage w and v in LDS.
// Phase 2 (lane -> g = lane&15, k-quad): w1/w2 matvecs + softmax over K.
// Phase 3 (lane = channel c): out[c] = sum_k v[k][c] * soft[k][c%16].
// ---------------------------------------------------------------------------
__global__ __launch_bounds__(64) void attn_kernel(
    const float* __restrict__ coord, const int* __restrict__ nbr,
    const float* __restrict__ xq_t, const float* __restrict__ xk_t,
    const float* __restrict__ xv_t,
    const float* __restrict__ p1_w, const float* __restrict__ p1_b,
    const float* __restrict__ p_bn_g, const float* __restrict__ p_bn_b,
    const float* __restrict__ p_bn_m, const float* __restrict__ p_bn_v,
    const float* __restrict__ p2_w, const float* __restrict__ p2_b,
    const float* __restrict__ w_bn1_g, const float* __restrict__ w_bn1_b,
    const float* __restrict__ w_bn1_m, const float* __restrict__ w_bn1_v,
    const float* __restrict__ w1_w, const float* __restrict__ w1_b,
    const float* __restrict__ w_bn2_g, const float* __restrict__ w_bn2_b,
    const float* __restrict__ w_bn2_m, const float* __restrict__ w_bn2_v,
    const float* __restrict__ w2_w, const float* __restrict__ w2_b,
    float* __restrict__ out_t)
{
    constexpr int WS = 76;  // LDS row stride (floats), 16B-aligned
    constexpr int ZS = 18;
    __shared__ float wbuf[K_ * WS];
    __shared__ float vbuf[K_ * WS];
    __shared__ float zbuf[K_ * ZS];
    __shared__ float sbuf[K_ * ZS];

    int bn = blockIdx.x;          // = b*N + n
    int b  = bn / N_;
    int bB = b * N_;
    int c  = threadIdx.x;

    // per-lane constants, BN affine folded
    float xq   = xq_t[bn * C_ + c];
    float p2w0 = p2_w[c * 3 + 0], p2w1 = p2_w[c * 3 + 1], p2w2 = p2_w[c * 3 + 2];
    float p2b  = p2_b[c];
    float bn1s = w_bn1_g[c] * rsqrtf(w_bn1_v[c] + EPS_);
    float bn1b = w_bn1_b[c] - w_bn1_m[c] * bn1s;

    float p1w[9], pbs[3], pbb[3];
#pragma unroll
    for (int j = 0; j < 9; j++) p1w[j] = p1_w[j];
#pragma unroll
    for (int j = 0; j < 3; j++) {
        float s = p_bn_g[j] * rsqrtf(p_bn_v[j] + EPS_);
        pbs[j] = s;
        pbb[j] = (p1_b[j] - p_bn_m[j]) * s + p_bn_b[j];
    }

    // ---- phase 1: batched gather ----
    const int* nb = nbr + bn * K_;
    int idxs[K_];
#pragma unroll
    for (int kk = 0; kk < K_; kk++) idxs[kk] = nb[kk];   // wave-uniform -> s_load

    float cxs[K_], cys[K_], czs[K_], xks[K_], xvs[K_];
#pragma unroll
    for (int kk = 0; kk < K_; kk++) {
        int src = bB + idxs[kk];
        const float* cp = coord + (size_t)src * 3;
        cxs[kk] = cp[0];
        cys[kk] = cp[1];
        czs[kk] = cp[2];
        xks[kk] = xk_t[(size_t)src * C_ + c];   // coalesced 256B row gather
        xvs[kk] = xv_t[(size_t)src * C_ + c];
    }

#pragma unroll
    for (int kk = 0; kk < K_; kk++) {
        float cx = cxs[kk], cy = cys[kk], cz = czs[kk];
        float h0 = fmaxf(0.f, (p1w[0]*cx + p1w[1]*cy + p1w[2]*cz) * pbs[0] + pbb[0]);
        float h1 = fmaxf(0.f, (p1w[3]*cx + p1w[4]*cy + p1w[5]*cz) * pbs[1] + pbb[1]);
        float h2 = fmaxf(0.f, (p1w[6]*cx + p1w[7]*cy + p1w[8]*cz) * pbs[2] + pbb[2]);
        float pr = fmaf(p2w0, h0, fmaf(p2w1, h1, fmaf(p2w2, h2, p2b)));
        wbuf[kk * WS + c] = fmaxf(0.f, (xks[kk] - xq + pr) * bn1s + bn1b);
        vbuf[kk * WS + c] = xvs[kk] + pr;
    }
    __syncthreads();

    // ---- phase 2a: u[g, k] = w1_w[g,:] . wbuf[k,:] ----
    int g  = c & 15;
    int kb = (c >> 4) * 4;
    float u0 = 0.f, u1 = 0.f, u2 = 0.f, u3 = 0.f;
    const float4* w1r = reinterpret_cast<const float4*>(w1_w + g * C_);
#pragma unroll
    for (int c4 = 0; c4 < 16; c4++) {
        float4 wr = w1r[c4];
        float4 b0 = *reinterpret_cast<const float4*>(&wbuf[(kb + 0) * WS + c4 * 4]);
        float4 b1 = *reinterpret_cast<const float4*>(&wbuf[(kb + 1) * WS + c4 * 4]);
        float4 b2 = *reinterpret_cast<const float4*>(&wbuf[(kb + 2) * WS + c4 * 4]);
        float4 b3 = *reinterpret_cast<const float4*>(&wbuf[(kb + 3) * WS + c4 * 4]);
        u0 = fmaf(wr.x, b0.x, u0); u0 = fmaf(wr.y, b0.y, u0); u0 = fmaf(wr.z, b0.z, u0); u0 = fmaf(wr.w, b0.w, u0);
        u1 = fmaf(wr.x, b1.x, u1); u1 = fmaf(wr.y, b1.y, u1); u1 = fmaf(wr.z, b1.z, u1); u1 = fmaf(wr.w, b1.w, u1);
        u2 = fmaf(wr.x, b2.x, u2); u2 = fmaf(wr.y, b2.y, u2); u2 = fmaf(wr.z, b2.z, u2); u2 = fmaf(wr.w, b2.w, u2);
        u3 = fmaf(wr.x, b3.x, u3); u3 = fmaf(wr.y, b3.y, u3); u3 = fmaf(wr.z, b3.z, u3); u3 = fmaf(wr.w, b3.w, u3);
    }
    float w1bb = w1_b[g];
    float bn2s = w_bn2_g[g] * rsqrtf(w_bn2_v[g] + EPS_);
    float bn2b = w_bn2_b[g] - w_bn2_m[g] * bn2s;
    zbuf[(kb + 0) * ZS + g] = fmaxf(0.f, (u0 + w1bb) * bn2s + bn2b);
    zbuf[(kb + 1) * ZS + g] = fmaxf(0.f, (u1 + w1bb) * bn2s + bn2b);
    zbuf[(kb + 2) * ZS + g] = fmaxf(0.f, (u2 + w1bb) * bn2s + bn2b);
    zbuf[(kb + 3) * ZS + g] = fmaxf(0.f, (u3 + w1bb) * bn2s + bn2b);
    __syncthreads();

    // ---- phase 2b: t[g, k] = w2_b[g] + sum_gg w2_w[g,gg] * z[gg, k] ----
    float t0 = w2_b[g], t1 = t0, t2 = t0, t3 = t0;
#pragma unroll
    for (int gg = 0; gg < 16; gg++) {
        float w2 = w2_w[g * 16 + gg];
        t0 = fmaf(w2, zbuf[(kb + 0) * ZS + gg], t0);
        t1 = fmaf(w2, zbuf[(kb + 1) * ZS + gg], t1);
        t2 = fmaf(w2, zbuf[(kb + 2) * ZS + gg], t2);
        t3 = fmaf(w2, zbuf[(kb + 3) * ZS + gg], t3);
    }

    // softmax over the 16 k's: 4 local + lanes {g, g+16, g+32, g+48}
    float m = fmaxf(fmaxf(t0, t1), fmaxf(t2, t3));
    m = fmaxf(m, __shfl_xor(m, 16));
    m = fmaxf(m, __shfl_xor(m, 32));
    float e0 = expf(t0 - m), e1 = expf(t1 - m), e2 = expf(t2 - m), e3 = expf(t3 - m);
    float s = e0 + e1 + e2 + e3;
    s += __shfl_xor(s, 16);
    s += __shfl_xor(s, 32);
    float inv = 1.0f / s;
    sbuf[(kb + 0) * ZS + g] = e0 * inv;
    sbuf[(kb + 1) * ZS + g] = e1 * inv;
    sbuf[(kb + 2) * ZS + g] = e2 * inv;
    sbuf[(kb + 3) * ZS + g] = e3 * inv;
    __syncthreads();

    // ---- phase 3: out[c] = sum_k v[k][c] * soft[k][c & 15] ----
    float acc = 0.f;
#pragma unroll
    for (int kk = 0; kk < K_; kk++)
        acc = fmaf(vbuf[kk * WS + c], sbuf[kk * ZS + g], acc);
    out_t[bn * C_ + c] = acc;   // coalesced [point][channel]
}

// ---------------------------------------------------------------------------
// Kernel C: transpose [B, N, C] -> [B, C, N], 64x64 LDS tiles.
// ---------------------------------------------------------------------------
__global__ __launch_bounds__(256) void transpose_kernel(const float* __restrict__ src,
                                                        float* __restrict__ dst)
{
    __shared__ float tile[64][65];
    int b  = blockIdx.y;
    int n0 = blockIdx.x * 64;
    int t  = threadIdx.x;

    int p  = t >> 2;
    int c0 = (t & 3) * 16;
    int n  = n0 + p;
    if (n < N_) {
        const float4* s = reinterpret_cast<const float4*>(src + ((size_t)b * N_ + n) * C_ + c0);
#pragma unroll
        for (int j = 0; j < 4; j++) {
            float4 v = s[j];
            tile[p][c0 + j * 4 + 0] = v.x;
            tile[p][c0 + j * 4 + 1] = v.y;
            tile[p][c0 + j * 4 + 2] = v.z;
            tile[p][c0 + j * 4 + 3] = v.w;
        }
    }
    __syncthreads();

    int n_off = t & 63;
    int cg    = t >> 6;   // 0..3
    if (n0 + n_off < N_) {
#pragma unroll
        for (int j = 0; j < 16; j++) {
            int cc = cg * 16 + j;
            dst[(size_t)b * C_ * N_ + (size_t)cc * N_ + n0 + n_off] = tile[n_off][cc];
        }
    }
}

// ---------------------------------------------------------------------------
extern "C" void kernel_launch(void* const* d_in, const int* in_sizes, int n_in,
                              void* d_out, int out_size, void* d_ws, size_t ws_size,
                              hipStream_t stream)
{
    const float* coord = (const float*)d_in[0];
    const float* q     = (const float*)d_in[1];
    const float* k     = (const float*)d_in[2];
    const int*   nbr   = (const int*)d_in[3];
    const float* wq = (const float*)d_in[4];
    const float* bq = (const float*)d_in[5];
    const float* wk = (const float*)d_in[6];
    const float* bk = (const float*)d_in[7];
    const float* wv = (const float*)d_in[8];
    const float* bv = (const float*)d_in[9];
    const float* p1_w = (const float*)d_in[10];
    const float* p1_b = (const float*)d_in[11];
    const float* p_bn_g = (const float*)d_in[12];
    const float* p_bn_b = (const float*)d_in[13];
    const float* p_bn_m = (const float*)d_in[14];
    const float* p_bn_v = (const float*)d_in[15];
    const float* p2_w = (const float*)d_in[16];
    const float* p2_b = (const float*)d_in[17];
    const float* w_bn1_g = (const float*)d_in[18];
    const float* w_bn1_b = (const float*)d_in[19];
    const float* w_bn1_m = (const float*)d_in[20];
    const float* w_bn1_v = (const float*)d_in[21];
    const float* w1_w = (const float*)d_in[22];
    const float* w1_b = (const float*)d_in[23];
    const float* w_bn2_g = (const float*)d_in[24];
    const float* w_bn2_b = (const float*)d_in[25];
    const float* w_bn2_m = (const float*)d_in[26];
    const float* w_bn2_v = (const float*)d_in[27];
    const float* w2_w = (const float*)d_in[28];
    const float* w2_b = (const float*)d_in[29];

    const size_t PTS = (size_t)B_ * N_;        // 40000
    float* ws   = (float*)d_ws;
    float* xq_t = ws;                          // [PTS][64]
    float* xk_t = ws + PTS * C_;               // [PTS][64]
    float* xv_t = ws + 2 * PTS * C_;           // [PTS][64]
    float* out_t = xq_t;  // safe alias: block bn reads xq_t[bn] before writing out_t[bn]

    proj_kernel<<<(B_ * N_) / 64, 256, 0, stream>>>(
        q, k, wq, bq, wk, bk, wv, bv, xq_t, xk_t, xv_t);

    attn_kernel<<<B_ * N_, 64, 0, stream>>>(
        coord, nbr, xq_t, xk_t, xv_t,
        p1_w, p1_b, p_bn_g, p_bn_b, p_bn_m, p_bn_v, p2_w, p2_b,
        w_bn1_g, w_bn1_b, w_bn1_m, w_bn1_v, w1_w, w1_b,
        w_bn2_g, w_bn2_b, w_bn2_m, w_bn2_v, w2_w, w2_b,
        out_t);

    transpose_kernel<<<dim3((N_ + 63) / 64, B_), 256, 0, stream>>>(
        out_t, (float*)d_out);
}